// Round 14
// baseline (389.536 us; speedup 1.0000x reference)
//
#include <hip/hip_runtime.h>
#include <hip/hip_fp16.h>
#include <hip/hip_cooperative_groups.h>

namespace cg = cooperative_groups;

#define NEG_SLOPE 0.2f

typedef __fp16 half8v __attribute__((ext_vector_type(8)));
typedef __fp16 half4v __attribute__((ext_vector_type(4)));
typedef float f32x4 __attribute__((ext_vector_type(4)));
typedef unsigned uint4u __attribute__((ext_vector_type(4), aligned(4)));
typedef float f32x4u __attribute__((ext_vector_type(4), aligned(4)));

__device__ __forceinline__ float lrelu(float x) {
    return fmaxf(x, 0.0f) + NEG_SLOPE * fminf(x, 0.0f);
}

__device__ __forceinline__ unsigned fkey(float f) {
    unsigned u = __float_as_uint(f);
    return (u & 0x80000000u) ? ~u : (u | 0x80000000u);
}
__device__ __forceinline__ float funkey(unsigned k) {
    return __uint_as_float((k & 0x80000000u) ? (k & 0x7fffffffu) : ~k);
}

// ---------------- scan: 2 kernels (write self-computes block offset) ----------------

__global__ __launch_bounds__(256) void scan_reduce(const int* __restrict__ cnt,
                                                   int* __restrict__ bsum, int n) {
    __shared__ int sm[256];
    int base = blockIdx.x * 1024 + threadIdx.x * 4;
    int s = 0;
#pragma unroll
    for (int j = 0; j < 4; ++j) {
        int i = base + j;
        if (i < n) s += cnt[i];
    }
    sm[threadIdx.x] = s;
    __syncthreads();
#pragma unroll
    for (int off = 128; off >= 1; off >>= 1) {
        if (threadIdx.x < off) sm[threadIdx.x] += sm[threadIdx.x + off];
        __syncthreads();
    }
    if (threadIdx.x == 0) bsum[blockIdx.x] = sm[0];
}

// bsum holds per-block totals; each block sums bsum[0..blk) itself (nb <= 256).
__global__ __launch_bounds__(256) void scan_write2(const int* __restrict__ cnt,
                                                   const int* __restrict__ bsum,
                                                   int* __restrict__ rp, int n) {
    __shared__ int sm[256];
    __shared__ int boff;
    int tid = threadIdx.x;
    int partial = (tid < blockIdx.x) ? bsum[tid] : 0;
    sm[tid] = partial;
    __syncthreads();
#pragma unroll
    for (int off = 128; off >= 1; off >>= 1) {
        if (tid < off) sm[tid] += sm[tid + off];
        __syncthreads();
    }
    if (tid == 0) boff = sm[0];
    __syncthreads();

    int base = blockIdx.x * 1024 + tid * 4;
    int v[4];
    int s = 0;
#pragma unroll
    for (int j = 0; j < 4; ++j) {
        int i = base + j;
        v[j] = (i < n) ? cnt[i] : 0;
        s += v[j];
    }
    sm[tid] = s;
    __syncthreads();
#pragma unroll
    for (int off = 1; off < 256; off <<= 1) {
        int y = (tid >= off) ? sm[tid - off] : 0;
        __syncthreads();
        sm[tid] += y;
        __syncthreads();
    }
    int run = sm[tid] - s + boff;
#pragma unroll
    for (int j = 0; j < 4; ++j) {
        int i = base + j;
        if (i < n) {
            rp[i] = run;
            run += v[j];
            if (i == n - 1) rp[n] = run;
        }
    }
}

// ---------------- radix passes (1024 items / block) ----------------

__global__ __launch_bounds__(256) void rhist1_kernel(const int* __restrict__ dst,
                                                     int* __restrict__ h, int E, int nblk) {
    __shared__ int lh[256];
    lh[threadIdx.x] = 0;
    __syncthreads();
    int base = blockIdx.x * 1024;
#pragma unroll
    for (int j = 0; j < 4; ++j) {
        int i = base + j * 256 + threadIdx.x;
        if (i < E) atomicAdd(&lh[dst[i] & 255], 1);
    }
    __syncthreads();
    h[threadIdx.x * nblk + blockIdx.x] = lh[threadIdx.x];
}

__global__ __launch_bounds__(256) void rhist2_kernel(const unsigned* __restrict__ kv,
                                                     int* __restrict__ h, int E, int nblk) {
    __shared__ int lh[256];
    lh[threadIdx.x] = 0;
    __syncthreads();
    int base = blockIdx.x * 1024;
#pragma unroll
    for (int j = 0; j < 4; ++j) {
        int i = base + j * 256 + threadIdx.x;
        if (i < E) atomicAdd(&lh[kv[i] >> 24], 1);
    }
    __syncthreads();
    h[threadIdx.x * nblk + blockIdx.x] = lh[threadIdx.x];
}

template <int SH, bool PACK>
__global__ __launch_bounds__(256) void rscat_kernel(const unsigned* __restrict__ in,
                                                    const int* __restrict__ srcp,
                                                    const int* __restrict__ dstp,
                                                    unsigned* __restrict__ outv,
                                                    const int* __restrict__ scanned,
                                                    int E, int nblk) {
    __shared__ unsigned items[1024];
    __shared__ unsigned sorted[1024];
    __shared__ int lh[256], lstart[256], rbase[256];
    __shared__ int wcnt[4][256];

    int tid = threadIdx.x, blk = blockIdx.x;
    int base = blk * 1024;
    int k = min(1024, E - base);
    lh[tid] = 0;
    rbase[tid] = 0;
#pragma unroll
    for (int j = 0; j < 4; ++j) {
        int idx = j * 256 + tid;
        unsigned v = 0u;
        if (base + idx < E) {
            if constexpr (PACK)
                v = ((unsigned)dstp[base + idx] << 16) | (unsigned)srcp[base + idx];
            else
                v = in[base + idx];
        }
        items[idx] = v;
    }
    __syncthreads();
#pragma unroll
    for (int j = 0; j < 4; ++j) {
        int idx = j * 256 + tid;
        if (idx < k) atomicAdd(&lh[(items[idx] >> SH) & 255], 1);
    }
    __syncthreads();
    int sv = lh[tid];
    lstart[tid] = sv;
    __syncthreads();
    for (int off = 1; off < 256; off <<= 1) {
        int y = (tid >= off) ? lstart[tid - off] : 0;
        __syncthreads();
        lstart[tid] += y;
        __syncthreads();
    }
    int excl = lstart[tid] - sv;
    __syncthreads();
    lstart[tid] = excl;
    __syncthreads();

    int lane = tid & 63, wave = tid >> 6;
#pragma unroll
    for (int it = 0; it < 4; ++it) {
        int idx = it * 256 + tid;
        unsigned v = items[idx];
        int d = (v >> SH) & 255;
        bool valid = idx < k;
        unsigned long long m = __ballot(valid);
#pragma unroll
        for (int b = 0; b < 8; ++b) {
            unsigned long long bb = __ballot((d >> b) & 1);
            m &= ((d >> b) & 1) ? bb : ~bb;
        }
        int lanerank = __popcll(m & ((1ull << lane) - 1ull));
        int wtot = __popcll(m);
        wcnt[0][tid] = 0; wcnt[1][tid] = 0; wcnt[2][tid] = 0; wcnt[3][tid] = 0;
        __syncthreads();
        if (valid && lanerank == 0) wcnt[wave][d] = wtot;
        __syncthreads();
        if (valid) {
            int cw = 0;
            for (int w = 0; w < wave; ++w) cw += wcnt[w][d];
            sorted[lstart[d] + rbase[d] + cw + lanerank] = v;
        }
        __syncthreads();
        rbase[tid] += wcnt[0][tid] + wcnt[1][tid] + wcnt[2][tid] + wcnt[3][tid];
        __syncthreads();
    }
#pragma unroll
    for (int j = 0; j < 4; ++j) {
        int i = j * 256 + tid;
        if (i < k) {
            unsigned v = sorted[i];
            int d = (v >> SH) & 255;
            outv[scanned[d * nblk + blk] + (i - lstart[d])] = v;
        }
    }
}

// ---------------- row pointers from sorted kv ----------------

__global__ void rp_kernel(const unsigned* __restrict__ kv, int* __restrict__ rp,
                          int E, int N) {
    int i = blockIdx.x * 256 + threadIdx.x;
    if (i >= E) return;
    int cur = (int)(kv[i] >> 16);
    int prev = (i == 0) ? -1 : (int)(kv[i - 1] >> 16);
    for (int t = prev + 1; t <= cur; ++t) rp[t] = i;
    if (i == E - 1)
        for (int t = cur + 1; t <= N; ++t) rp[t] = E;
}

// ---------------- cooperative: al1 + per-head gmax + w1 ----------------
// Phase 1: al logits + per-block per-head max (plain stores). Phase 2: block 0
// reduces bmax -> gm (plain store). Phase 3: edge weights (fp16, transposed).

__global__ __launch_bounds__(256, 4) void al1_w1_fused(
    const __half* __restrict__ h1h, const float* __restrict__ as,
    const float* __restrict__ ad, float* __restrict__ alS, float* __restrict__ alD,
    unsigned* __restrict__ bmax, unsigned* __restrict__ gm,
    const unsigned* __restrict__ kv, __half* __restrict__ w1t, int N, int E) {
    cg::grid_group grid = cg::this_grid();
    __shared__ unsigned smu[256];
    int tid = threadIdx.x;
    int stride = gridDim.x * 256;

    unsigned loc = 0;
    for (int g = blockIdx.x * 256 + tid; g < N * 8; g += stride) {
        int r = g >> 3, h = g & 7;
        const __half2* hp = (const __half2*)(h1h + (size_t)r * 128 + h * 16);
        const float* sp = as + h * 16;
        const float* dp = ad + h * 16;
        float s = 0.f, d = 0.f;
#pragma unroll
        for (int q = 0; q < 8; ++q) {
            float2 v = __half22float2(hp[q]);
            s = fmaf(v.x, sp[2 * q], s);
            d = fmaf(v.x, dp[2 * q], d);
            s = fmaf(v.y, sp[2 * q + 1], s);
            d = fmaf(v.y, dp[2 * q + 1], d);
        }
        alS[g] = s;
        alD[g] = d;
        loc = max(loc, fkey(s));
    }
    // head of every element this thread touched is tid&7 (strides are multiples of 8)
    smu[tid] = loc;
    __syncthreads();
#pragma unroll
    for (int off = 128; off >= 8; off >>= 1) {
        if (tid < off) smu[tid] = max(smu[tid], smu[tid + off]);
        __syncthreads();
    }
    if (tid < 8) bmax[blockIdx.x * 8 + tid] = smu[tid];
    grid.sync();

    if (blockIdx.x == 0) {
        unsigned m = 0;
        int total = gridDim.x * 8;
        for (int i = tid; i < total; i += 256) m = max(m, bmax[i]);
        smu[tid] = m;
        __syncthreads();
#pragma unroll
        for (int off = 128; off >= 8; off >>= 1) {
            if (tid < off) smu[tid] = max(smu[tid], smu[tid + off]);
            __syncthreads();
        }
        if (tid < 8) gm[tid] = smu[tid];
    }
    grid.sync();

    float gmv[8];
#pragma unroll
    for (int h = 0; h < 8; ++h) gmv[h] = funkey(gm[h]);

    for (int e = blockIdx.x * 256 + tid; e < E; e += stride) {
        unsigned k = kv[e];
        int s = (int)(k & 0xFFFFu), t = (int)(k >> 16);
        float sv[8], dv[8];
        *(f32x4*)&sv[0] = *(const f32x4*)(alS + (size_t)s * 8);
        *(f32x4*)&sv[4] = *(const f32x4*)(alS + (size_t)s * 8 + 4);
        *(f32x4*)&dv[0] = *(const f32x4*)(alD + (size_t)t * 8);
        *(f32x4*)&dv[4] = *(const f32x4*)(alD + (size_t)t * 8 + 4);
#pragma unroll
        for (int h = 0; h < 8; ++h) {
            float m = lrelu(gmv[h] + dv[h]);
            w1t[(size_t)h * E + e] = __float2half(__expf(lrelu(sv[h] + dv[h]) - m));
        }
    }
}

// ---------------- cooperative: gmax2 + w2 ----------------

__global__ __launch_bounds__(256, 4) void gmax2_w2_fused(
    const float* __restrict__ alS, const float* __restrict__ alD,
    unsigned* __restrict__ bmax, unsigned* __restrict__ gm,
    const unsigned* __restrict__ kv, float* __restrict__ w2v, int N, int E) {
    cg::grid_group grid = cg::this_grid();
    __shared__ unsigned smu[256];
    int tid = threadIdx.x;
    int stride = gridDim.x * 256;

    unsigned loc = 0;
    for (int i = blockIdx.x * 256 + tid; i < N; i += stride) loc = max(loc, fkey(alS[i]));
    smu[tid] = loc;
    __syncthreads();
#pragma unroll
    for (int off = 128; off >= 1; off >>= 1) {
        if (tid < off) smu[tid] = max(smu[tid], smu[tid + off]);
        __syncthreads();
    }
    if (tid == 0) bmax[blockIdx.x] = smu[0];
    grid.sync();

    if (blockIdx.x == 0) {
        unsigned m = 0;
        for (int i = tid; i < gridDim.x; i += 256) m = max(m, bmax[i]);
        smu[tid] = m;
        __syncthreads();
#pragma unroll
        for (int off = 128; off >= 1; off >>= 1) {
            if (tid < off) smu[tid] = max(smu[tid], smu[tid + off]);
            __syncthreads();
        }
        if (tid == 0) gm[0] = smu[0];
    }
    grid.sync();

    float gmv = funkey(gm[0]);
    for (int e = blockIdx.x * 256 + tid; e < E; e += stride) {
        unsigned k = kv[e];
        int s = (int)(k & 0xFFFFu), t = (int)(k >> 16);
        float adT = alD[t];
        w2v[e] = __expf(lrelu(alS[s] + adT) - lrelu(gmv + adT));
    }
}

// ---------------- MFMA GEMM: C[M,128(half)] = A[M,128] @ B[128,NC(f32)] ------------

template <int NC, typename AT, bool FUSE_AL2>
__global__ __launch_bounds__(256) void gemm_mfma(const AT* __restrict__ A,
                                                 const float* __restrict__ B,
                                                 __half* __restrict__ C, int M,
                                                 const float* __restrict__ as,
                                                 const float* __restrict__ ad,
                                                 float* __restrict__ alS,
                                                 float* __restrict__ alD) {
    __shared__ __half Bt[128][136];

    {
        int t = threadIdx.x;
        int c = t & 127;
        int kq = t >> 7;
#pragma unroll
        for (int ch = 0; ch < 8; ++ch) {
            int k0 = kq * 64 + ch * 8;
            half8v hv;
#pragma unroll
            for (int j = 0; j < 8; ++j) {
                float v = (c < NC) ? B[(size_t)(k0 + j) * NC + c] : 0.0f;
                hv[j] = (__fp16)v;
            }
            *(half8v*)&Bt[c][k0] = hv;
        }
    }
    __syncthreads();

    const int wid = threadIdx.x >> 6;
    const int lane = threadIdx.x & 63;
    const int li = lane & 15;
    const int lg = lane >> 4;

    int row = blockIdx.x * 64 + wid * 16 + li;
    int rowc = min(row, M - 1);

    half8v a[4];
#pragma unroll
    for (int ks = 0; ks < 4; ++ks) {
        int q = ks * 4 + lg;
        if constexpr (sizeof(AT) == 2) {
            a[ks] = *((const half8v*)(A + (size_t)rowc * 128) + q);
        } else {
            const float4* p = (const float4*)(A + (size_t)rowc * 128) + 2 * q;
            float4 a0 = p[0], a1 = p[1];
            half8v hv;
            hv[0] = (__fp16)a0.x; hv[1] = (__fp16)a0.y; hv[2] = (__fp16)a0.z; hv[3] = (__fp16)a0.w;
            hv[4] = (__fp16)a1.x; hv[5] = (__fp16)a1.y; hv[6] = (__fp16)a1.z; hv[7] = (__fp16)a1.w;
            a[ks] = hv;
        }
    }

    f32x4 acc[8];
#pragma unroll
    for (int ct = 0; ct < 8; ++ct) acc[ct] = (f32x4)0.0f;

#pragma unroll
    for (int ks = 0; ks < 4; ++ks) {
#pragma unroll
        for (int ct = 0; ct < 8; ++ct) {
            half8v b = *(const half8v*)&Bt[ct * 16 + li][ks * 32 + 8 * lg];
            acc[ct] = __builtin_amdgcn_mfma_f32_16x16x32_f16(a[ks], b, acc[ct], 0, 0, 0);
        }
    }

    int orow = blockIdx.x * 64 + wid * 16 + 4 * lg;
#pragma unroll
    for (int ct = 0; ct < 8; ++ct) {
#pragma unroll
        for (int r = 0; r < 4; ++r) {
            int rr = orow + r;
            if (rr < M) C[(size_t)rr * 128 + ct * 16 + li] = __float2half(acc[ct][r]);
        }
    }

    if constexpr (FUSE_AL2) {
        float asv[8], adv[8];
#pragma unroll
        for (int ct = 0; ct < 8; ++ct) {
            int c = ct * 16 + li;
            asv[ct] = (c < NC) ? as[c] : 0.0f;
            adv[ct] = (c < NC) ? ad[c] : 0.0f;
        }
#pragma unroll
        for (int r = 0; r < 4; ++r) {
            float s = 0.f, d = 0.f;
#pragma unroll
            for (int ct = 0; ct < 8; ++ct) {
                s = fmaf(acc[ct][r], asv[ct], s);
                d = fmaf(acc[ct][r], adv[ct], d);
            }
            s += __shfl_down(s, 8); d += __shfl_down(d, 8);
            s += __shfl_down(s, 4); d += __shfl_down(d, 4);
            s += __shfl_down(s, 2); d += __shfl_down(d, 2);
            s += __shfl_down(s, 1); d += __shfl_down(d, 1);
            if (li == 0) {
                int rr = orow + r;
                if (rr < M) { alS[rr] = s; alD[rr] = d; }
            }
        }
    }
}

// ---------------- layer-1 aggregation: fp16 weights, unroll 16/8/4/1 ----------------

__global__ __launch_bounds__(256) void agg1_kernel(
    const __half* __restrict__ h1h, const float* __restrict__ alS,
    const float* __restrict__ alD, const float* __restrict__ b1,
    const int* __restrict__ rp, const unsigned* __restrict__ kv,
    const __half* __restrict__ w1t, const unsigned* __restrict__ gm,
    __half* __restrict__ h2h, int N, int E) {
    int t = blockIdx.x * 4 + (threadIdx.x >> 6);
    int lane = threadIdx.x & 63;
    int h = lane >> 3;

    float adh = alD[t * 8 + h];
    float mh = lrelu(funkey(gm[h]) + adh);
    int e0 = rp[t], e1 = rp[t + 1];

    float ex = __expf(lrelu(alS[t * 8 + h] + adh) - mh);  // self loop (fp32)
    float dsum = ex, dsum2 = 0.f;
    float2 hs = __half22float2(*(const __half2*)(h1h + (size_t)t * 128 + 2 * lane));
    float fx = ex * hs.x, fy = ex * hs.y;
    const __half* wrow = w1t + (size_t)h * E;

    int e = e0;
    while (e < e1 && (e & 3)) {
        int s0 = (int)(kv[e] & 0xFFFFu);
        float w0 = __half2float(wrow[e]);
        float2 f0 = __half22float2(*(const __half2*)(h1h + (size_t)s0 * 128 + 2 * lane));
        dsum2 += w0;
        fx = fmaf(w0, f0.x, fx); fy = fmaf(w0, f0.y, fy);
        ++e;
    }
    for (; e + 16 <= e1; e += 16) {
        uint4u kk[4];
        float ww[16];
#pragma unroll
        for (int q = 0; q < 4; ++q) {
            kk[q] = *(const uint4u*)&kv[e + 4 * q];
            half4v wv = *(const half4v*)&wrow[e + 4 * q];
#pragma unroll
            for (int r = 0; r < 4; ++r) ww[q * 4 + r] = (float)wv[r];
        }
        float2 ff[16];
#pragma unroll
        for (int q = 0; q < 4; ++q)
#pragma unroll
            for (int r = 0; r < 4; ++r)
                ff[q * 4 + r] = __half22float2(
                    *(const __half2*)(h1h + (size_t)(kk[q][r] & 0xFFFFu) * 128 + 2 * lane));
#pragma unroll
        for (int q = 0; q < 4; ++q) {
            if (q & 1) dsum2 += (ww[q * 4] + ww[q * 4 + 1]) + (ww[q * 4 + 2] + ww[q * 4 + 3]);
            else       dsum  += (ww[q * 4] + ww[q * 4 + 1]) + (ww[q * 4 + 2] + ww[q * 4 + 3]);
#pragma unroll
            for (int r = 0; r < 4; ++r) {
                float w = ww[q * 4 + r];
                float2 f = ff[q * 4 + r];
                fx = fmaf(w, f.x, fx);
                fy = fmaf(w, f.y, fy);
            }
        }
    }
    if (e + 8 <= e1) {
        uint4u ka = *(const uint4u*)&kv[e];
        uint4u kb = *(const uint4u*)&kv[e + 4];
        half4v wva = *(const half4v*)&wrow[e];
        half4v wvb = *(const half4v*)&wrow[e + 4];
        float2 f0 = __half22float2(*(const __half2*)(h1h + (size_t)(ka.x & 0xFFFFu) * 128 + 2 * lane));
        float2 f1 = __half22float2(*(const __half2*)(h1h + (size_t)(ka.y & 0xFFFFu) * 128 + 2 * lane));
        float2 f2 = __half22float2(*(const __half2*)(h1h + (size_t)(ka.z & 0xFFFFu) * 128 + 2 * lane));
        float2 f3 = __half22float2(*(const __half2*)(h1h + (size_t)(ka.w & 0xFFFFu) * 128 + 2 * lane));
        float2 f4 = __half22float2(*(const __half2*)(h1h + (size_t)(kb.x & 0xFFFFu) * 128 + 2 * lane));
        float2 f5 = __half22float2(*(const __half2*)(h1h + (size_t)(kb.y & 0xFFFFu) * 128 + 2 * lane));
        float2 f6 = __half22float2(*(const __half2*)(h1h + (size_t)(kb.z & 0xFFFFu) * 128 + 2 * lane));
        float2 f7 = __half22float2(*(const __half2*)(h1h + (size_t)(kb.w & 0xFFFFu) * 128 + 2 * lane));
        float w0 = (float)wva[0], w1 = (float)wva[1], w2 = (float)wva[2], w3 = (float)wva[3];
        float w4 = (float)wvb[0], w5 = (float)wvb[1], w6 = (float)wvb[2], w7 = (float)wvb[3];
        dsum += (w0 + w1) + (w2 + w3);
        dsum2 += (w4 + w5) + (w6 + w7);
        fx = fmaf(w0, f0.x, fx); fy = fmaf(w0, f0.y, fy);
        fx = fmaf(w1, f1.x, fx); fy = fmaf(w1, f1.y, fy);
        fx = fmaf(w2, f2.x, fx); fy = fmaf(w2, f2.y, fy);
        fx = fmaf(w3, f3.x, fx); fy = fmaf(w3, f3.y, fy);
        fx = fmaf(w4, f4.x, fx); fy = fmaf(w4, f4.y, fy);
        fx = fmaf(w5, f5.x, fx); fy = fmaf(w5, f5.y, fy);
        fx = fmaf(w6, f6.x, fx); fy = fmaf(w6, f6.y, fy);
        fx = fmaf(w7, f7.x, fx); fy = fmaf(w7, f7.y, fy);
        e += 8;
    }
    if (e + 4 <= e1) {
        uint4u ka = *(const uint4u*)&kv[e];
        half4v wva = *(const half4v*)&wrow[e];
        float2 f0 = __half22float2(*(const __half2*)(h1h + (size_t)(ka.x & 0xFFFFu) * 128 + 2 * lane));
        float2 f1 = __half22float2(*(const __half2*)(h1h + (size_t)(ka.y & 0xFFFFu) * 128 + 2 * lane));
        float2 f2 = __half22float2(*(const __half2*)(h1h + (size_t)(ka.z & 0xFFFFu) * 128 + 2 * lane));
        float2 f3 = __half22float2(*(const __half2*)(h1h + (size_t)(ka.w & 0xFFFFu) * 128 + 2 * lane));
        float w0 = (float)wva[0], w1 = (float)wva[1], w2 = (float)wva[2], w3 = (float)wva[3];
        dsum += (w0 + w1) + (w2 + w3);
        fx = fmaf(w0, f0.x, fx); fy = fmaf(w0, f0.y, fy);
        fx = fmaf(w1, f1.x, fx); fy = fmaf(w1, f1.y, fy);
        fx = fmaf(w2, f2.x, fx); fy = fmaf(w2, f2.y, fy);
        fx = fmaf(w3, f3.x, fx); fy = fmaf(w3, f3.y, fy);
        e += 4;
    }
    for (; e < e1; ++e) {
        int s0 = (int)(kv[e] & 0xFFFFu);
        float w0 = __half2float(wrow[e]);
        float2 f0 = __half22float2(*(const __half2*)(h1h + (size_t)s0 * 128 + 2 * lane));
        dsum2 += w0;
        fx = fmaf(w0, f0.x, fx); fy = fmaf(w0, f0.y, fy);
    }
    dsum += dsum2;
    float inv = 1.0f / dsum;
    float2 bb = *(const float2*)(b1 + 2 * lane);
    float ox = fmaxf(fmaf(fx, inv, bb.x), 0.0f);
    float oy = fmaxf(fmaf(fy, inv, bb.y), 0.0f);
    *(__half2*)(h2h + (size_t)t * 128 + 2 * lane) = __floats2half2_rn(ox, oy);
}

// ---------------- layer-2 aggregation: unroll 16/8/4/1 ----------------

__global__ __launch_bounds__(256) void agg2_kernel(
    const __half* __restrict__ h3h, const float* __restrict__ alS,
    const float* __restrict__ alD, const float* __restrict__ b2,
    const int* __restrict__ rp, const unsigned* __restrict__ kv,
    const float* __restrict__ w2v, const unsigned* __restrict__ gm,
    float* __restrict__ out, int N, int NC) {
    int t = blockIdx.x * 4 + (threadIdx.x >> 6);
    int lane = threadIdx.x & 63;

    float adT = alD[t];
    float m = lrelu(funkey(gm[0]) + adT);
    int e0 = rp[t], e1 = rp[t + 1];

    float ex = __expf(lrelu(alS[t] + adT) - m);
    float dsum = ex, dsum2 = 0.f;
    float2 hs = __half22float2(*(const __half2*)(h3h + (size_t)t * 128 + 2 * lane));
    float fx = ex * hs.x, fy = ex * hs.y;  // pad cols are 0

    int e = e0;
    for (; e + 16 <= e1; e += 16) {
        uint4u kk[4];
        f32x4u ww[4];
#pragma unroll
        for (int q = 0; q < 4; ++q) {
            kk[q] = *(const uint4u*)&kv[e + 4 * q];
            ww[q] = *(const f32x4u*)&w2v[e + 4 * q];
        }
        float2 ff[16];
#pragma unroll
        for (int q = 0; q < 4; ++q)
#pragma unroll
            for (int r = 0; r < 4; ++r)
                ff[q * 4 + r] = __half22float2(
                    *(const __half2*)(h3h + (size_t)(kk[q][r] & 0xFFFFu) * 128 + 2 * lane));
#pragma unroll
        for (int q = 0; q < 4; ++q) {
            if (q & 1) dsum2 += (ww[q][0] + ww[q][1]) + (ww[q][2] + ww[q][3]);
            else       dsum  += (ww[q][0] + ww[q][1]) + (ww[q][2] + ww[q][3]);
#pragma unroll
            for (int r = 0; r < 4; ++r) {
                float w = ww[q][r];
                float2 f = ff[q * 4 + r];
                fx = fmaf(w, f.x, fx);
                fy = fmaf(w, f.y, fy);
            }
        }
    }
    if (e + 8 <= e1) {
        uint4u ka = *(const uint4u*)&kv[e];
        uint4u kb = *(const uint4u*)&kv[e + 4];
        f32x4u wa = *(const f32x4u*)&w2v[e];
        f32x4u wb = *(const f32x4u*)&w2v[e + 4];
        float2 f0 = __half22float2(*(const __half2*)(h3h + (size_t)(ka.x & 0xFFFFu) * 128 + 2 * lane));
        float2 f1 = __half22float2(*(const __half2*)(h3h + (size_t)(ka.y & 0xFFFFu) * 128 + 2 * lane));
        float2 f2 = __half22float2(*(const __half2*)(h3h + (size_t)(ka.z & 0xFFFFu) * 128 + 2 * lane));
        float2 f3 = __half22float2(*(const __half2*)(h3h + (size_t)(ka.w & 0xFFFFu) * 128 + 2 * lane));
        float2 f4 = __half22float2(*(const __half2*)(h3h + (size_t)(kb.x & 0xFFFFu) * 128 + 2 * lane));
        float2 f5 = __half22float2(*(const __half2*)(h3h + (size_t)(kb.y & 0xFFFFu) * 128 + 2 * lane));
        float2 f6 = __half22float2(*(const __half2*)(h3h + (size_t)(kb.z & 0xFFFFu) * 128 + 2 * lane));
        float2 f7 = __half22float2(*(const __half2*)(h3h + (size_t)(kb.w & 0xFFFFu) * 128 + 2 * lane));
        dsum += (wa[0] + wa[1]) + (wa[2] + wa[3]);
        dsum2 += (wb[0] + wb[1]) + (wb[2] + wb[3]);
        fx = fmaf(wa[0], f0.x, fx); fy = fmaf(wa[0], f0.y, fy);
        fx = fmaf(wa[1], f1.x, fx); fy = fmaf(wa[1], f1.y, fy);
        fx = fmaf(wa[2], f2.x, fx); fy = fmaf(wa[2], f2.y, fy);
        fx = fmaf(wa[3], f3.x, fx); fy = fmaf(wa[3], f3.y, fy);
        fx = fmaf(wb[0], f4.x, fx); fy = fmaf(wb[0], f4.y, fy);
        fx = fmaf(wb[1], f5.x, fx); fy = fmaf(wb[1], f5.y, fy);
        fx = fmaf(wb[2], f6.x, fx); fy = fmaf(wb[2], f6.y, fy);
        fx = fmaf(wb[3], f7.x, fx); fy = fmaf(wb[3], f7.y, fy);
        e += 8;
    }
    if (e + 4 <= e1) {
        uint4u ka = *(const uint4u*)&kv[e];
        f32x4u wa = *(const f32x4u*)&w2v[e];
        float2 f0 = __half22float2(*(const __half2*)(h3h + (size_t)(ka.x & 0xFFFFu) * 128 + 2 * lane));
        float2 f1 = __half22float2(*(const __half2*)(h3h + (size_t)(ka.y & 0xFFFFu) * 128 + 2 * lane));
        float2 f2 = __half22float2(*(const __half2*)(h3h + (size_t)(ka.z & 0xFFFFu) * 128 + 2 * lane));
        float2 f3 = __half22float2(*(const __half2*)(h3h + (size_t)(ka.w & 0xFFFFu) * 128 + 2 * lane));
        dsum += (wa[0] + wa[1]) + (wa[2] + wa[3]);
        fx = fmaf(wa[0], f0.x, fx); fy = fmaf(wa[0], f0.y, fy);
        fx = fmaf(wa[1], f1.x, fx); fy = fmaf(wa[1], f1.y, fy);
        fx = fmaf(wa[2], f2.x, fx); fy = fmaf(wa[2], f2.y, fy);
        fx = fmaf(wa[3], f3.x, fx); fy = fmaf(wa[3], f3.y, fy);
        e += 4;
    }
    for (; e < e1; ++e) {
        int s0 = (int)(kv[e] & 0xFFFFu);
        float w0 = w2v[e];
        float2 f0 = __half22float2(*(const __half2*)(h3h + (size_t)s0 * 128 + 2 * lane));
        dsum2 += w0;
        fx = fmaf(w0, f0.x, fx); fy = fmaf(w0, f0.y, fy);
    }
    dsum += dsum2;
    float inv = 1.0f / dsum;
    int c0 = 2 * lane, c1 = 2 * lane + 1;
    if (c0 < NC) out[(size_t)t * NC + c0] = fmaf(fx, inv, b2[c0]);
    if (c1 < NC) out[(size_t)t * NC + c1] = fmaf(fy, inv, b2[c1]);
}

// ---------------- host launcher ----------------

extern "C" void kernel_launch(void* const* d_in, const int* in_sizes, int n_in,
                              void* d_out, int out_size, void* d_ws, size_t ws_size,
                              hipStream_t stream) {
    const float* x   = (const float*)d_in[0];
    const int*   ei  = (const int*)d_in[1];
    const float* W1  = (const float*)d_in[2];
    const float* aS1 = (const float*)d_in[3];
    const float* aD1 = (const float*)d_in[4];
    const float* b1  = (const float*)d_in[5];
    const float* W2  = (const float*)d_in[6];
    const float* aS2 = (const float*)d_in[7];
    const float* aD2 = (const float*)d_in[8];
    const float* b2  = (const float*)d_in[9];
    float* out = (float*)d_out;

    const int N = in_sizes[0] / 128;   // 50000
    const int E = in_sizes[1] / 2;     // 800000
    const int NC2 = 121;

    const int NBLK = (E + 1023) / 1024;        // 782
    const int HN = 256 * NBLK;                 // 200192
    const int COOP = 512;

    size_t off = 0;
    auto alloc = [&](size_t bytes) {
        size_t o = off;
        off = (off + bytes + 255) & ~(size_t)255;
        return o;
    };
    char* ws = (char*)d_ws;
    unsigned* kv0  = (unsigned*)(ws + alloc((size_t)E * 4));
    unsigned* kv1  = (unsigned*)(ws + alloc((size_t)E * 4));
    int*      h    = (int*)(ws + alloc((size_t)(HN + 1) * 4));
    int*      bsum = (int*)(ws + alloc(256 * 4));
    int*      rp   = (int*)(ws + alloc((size_t)(N + 1) * 4));
    float*    alS1 = (float*)(ws + alloc((size_t)N * 8 * 4));
    float*    alD1 = (float*)(ws + alloc((size_t)N * 8 * 4));
    float*    alS2 = (float*)(ws + alloc((size_t)N * 4));
    float*    alD2 = (float*)(ws + alloc((size_t)N * 4));
    unsigned* gm1  = (unsigned*)(ws + alloc(8 * 4));
    unsigned* gm2  = (unsigned*)(ws + alloc(4));
    unsigned* bmax1 = (unsigned*)(ws + alloc((size_t)COOP * 8 * 4));
    unsigned* bmax2 = (unsigned*)(ws + alloc((size_t)COOP * 4));
    __half*   w1t  = (__half*)(ws + alloc((size_t)E * 8 * 2));
    __half*   h1h  = (__half*)(ws + alloc((size_t)N * 128 * 2));
    __half*   h2h  = (__half*)(ws + alloc((size_t)N * 128 * 2));
    int*      hs   = (int*)(ws + alloc((size_t)(HN + 1) * 4));
    __half*   h3h  = h1h;              // h1h dead after agg1; reuse
    float*    w2v  = (float*)kv1;      // kv1 dead after sort; reuse
    if (ws_size < off) return;

    const int* src = ei;
    const int* dst = ei + E;

    int eb = (E + 255) / 256;
    int snb = (HN + 1023) / 1024;  // 196 <= 256

    // radix sort by dst (bytes 2 then 3); pass1 packs (dst<<16)|src on the fly
    rhist1_kernel<<<NBLK, 256, 0, stream>>>(dst, h, E, NBLK);
    scan_reduce<<<snb, 256, 0, stream>>>(h, bsum, HN);
    scan_write2<<<snb, 256, 0, stream>>>(h, bsum, hs, HN);
    rscat_kernel<16, true><<<NBLK, 256, 0, stream>>>(nullptr, src, dst, kv1, hs, E, NBLK);
    rhist2_kernel<<<NBLK, 256, 0, stream>>>(kv1, h, E, NBLK);
    scan_reduce<<<snb, 256, 0, stream>>>(h, bsum, HN);
    scan_write2<<<snb, 256, 0, stream>>>(h, bsum, hs, HN);
    rscat_kernel<24, false><<<NBLK, 256, 0, stream>>>(kv1, nullptr, nullptr, kv0, hs, E, NBLK);
    rp_kernel<<<eb, 256, 0, stream>>>(kv0, rp, E, N);

    int gmb = (N + 63) / 64;
    int ab = (N + 3) / 4;
    gemm_mfma<128, float, false><<<gmb, 256, 0, stream>>>(x, W1, h1h, N,
                                                          nullptr, nullptr, nullptr, nullptr);
    {
        int Nv = N, Ev = E;
        void* args[] = {(void*)&h1h, (void*)&aS1, (void*)&aD1, (void*)&alS1, (void*)&alD1,
                        (void*)&bmax1, (void*)&gm1, (void*)&kv0, (void*)&w1t,
                        (void*)&Nv, (void*)&Ev};
        hipLaunchCooperativeKernel((const void*)al1_w1_fused, dim3(COOP), dim3(256),
                                   args, 0, stream);
    }
    agg1_kernel<<<ab, 256, 0, stream>>>(h1h, alS1, alD1, b1, rp, kv0, w1t, gm1, h2h, N, E);

    gemm_mfma<121, __half, true><<<gmb, 256, 0, stream>>>(h2h, W2, h3h, N,
                                                          aS2, aD2, alS2, alD2);
    {
        int Nv = N, Ev = E;
        void* args[] = {(void*)&alS2, (void*)&alD2, (void*)&bmax2, (void*)&gm2,
                        (void*)&kv0, (void*)&w2v, (void*)&Nv, (void*)&Ev};
        hipLaunchCooperativeKernel((const void*)gmax2_w2_fused, dim3(COOP), dim3(256),
                                   args, 0, stream);
    }
    agg2_kernel<<<ab, 256, 0, stream>>>(h3h, alS2, alD2, b2, rp, kv0, w2v, gm2, out, N, NC2);
}

// Round 15
// 198.234 us; speedup vs baseline: 1.9650x; 1.9650x over previous
//
#include <hip/hip_runtime.h>
#include <hip/hip_fp16.h>

#define NEG_SLOPE 0.2f

typedef __fp16 half8v __attribute__((ext_vector_type(8)));
typedef __fp16 half4v __attribute__((ext_vector_type(4)));
typedef float f32x4 __attribute__((ext_vector_type(4)));
typedef unsigned uint4u __attribute__((ext_vector_type(4), aligned(4)));
typedef float f32x4u __attribute__((ext_vector_type(4), aligned(4)));

__device__ __forceinline__ float lrelu(float x) {
    return fmaxf(x, 0.0f) + NEG_SLOPE * fminf(x, 0.0f);
}

__device__ __forceinline__ unsigned fkey(float f) {
    unsigned u = __float_as_uint(f);
    return (u & 0x80000000u) ? ~u : (u | 0x80000000u);
}
__device__ __forceinline__ float funkey(unsigned k) {
    return __uint_as_float((k & 0x80000000u) ? (k & 0x7fffffffu) : ~k);
}

// ---------------- scan: 2 kernels (write self-computes block offset) ----------------

__global__ __launch_bounds__(256) void scan_reduce(const int* __restrict__ cnt,
                                                   int* __restrict__ bsum, int n) {
    __shared__ int sm[256];
    int base = blockIdx.x * 1024 + threadIdx.x * 4;
    int s = 0;
#pragma unroll
    for (int j = 0; j < 4; ++j) {
        int i = base + j;
        if (i < n) s += cnt[i];
    }
    sm[threadIdx.x] = s;
    __syncthreads();
#pragma unroll
    for (int off = 128; off >= 1; off >>= 1) {
        if (threadIdx.x < off) sm[threadIdx.x] += sm[threadIdx.x + off];
        __syncthreads();
    }
    if (threadIdx.x == 0) bsum[blockIdx.x] = sm[0];
}

// bsum holds per-block totals; each block sums bsum[0..blk) itself (nb <= 256).
__global__ __launch_bounds__(256) void scan_write2(const int* __restrict__ cnt,
                                                   const int* __restrict__ bsum,
                                                   int* __restrict__ rp, int n) {
    __shared__ int sm[256];
    __shared__ int boff;
    int tid = threadIdx.x;
    int partial = (tid < blockIdx.x) ? bsum[tid] : 0;
    sm[tid] = partial;
    __syncthreads();
#pragma unroll
    for (int off = 128; off >= 1; off >>= 1) {
        if (tid < off) sm[tid] += sm[tid + off];
        __syncthreads();
    }
    if (tid == 0) boff = sm[0];
    __syncthreads();

    int base = blockIdx.x * 1024 + tid * 4;
    int v[4];
    int s = 0;
#pragma unroll
    for (int j = 0; j < 4; ++j) {
        int i = base + j;
        v[j] = (i < n) ? cnt[i] : 0;
        s += v[j];
    }
    sm[tid] = s;
    __syncthreads();
#pragma unroll
    for (int off = 1; off < 256; off <<= 1) {
        int y = (tid >= off) ? sm[tid - off] : 0;
        __syncthreads();
        sm[tid] += y;
        __syncthreads();
    }
    int run = sm[tid] - s + boff;
#pragma unroll
    for (int j = 0; j < 4; ++j) {
        int i = base + j;
        if (i < n) {
            rp[i] = run;
            run += v[j];
            if (i == n - 1) rp[n] = run;
        }
    }
}

// ---------------- radix passes (1024 items / block) ----------------

__global__ __launch_bounds__(256) void rhist1_kernel(const int* __restrict__ dst,
                                                     int* __restrict__ h, int E, int nblk) {
    __shared__ int lh[256];
    lh[threadIdx.x] = 0;
    __syncthreads();
    int base = blockIdx.x * 1024;
#pragma unroll
    for (int j = 0; j < 4; ++j) {
        int i = base + j * 256 + threadIdx.x;
        if (i < E) atomicAdd(&lh[dst[i] & 255], 1);
    }
    __syncthreads();
    h[threadIdx.x * nblk + blockIdx.x] = lh[threadIdx.x];
}

__global__ __launch_bounds__(256) void rhist2_kernel(const unsigned* __restrict__ kv,
                                                     int* __restrict__ h, int E, int nblk) {
    __shared__ int lh[256];
    lh[threadIdx.x] = 0;
    __syncthreads();
    int base = blockIdx.x * 1024;
#pragma unroll
    for (int j = 0; j < 4; ++j) {
        int i = base + j * 256 + threadIdx.x;
        if (i < E) atomicAdd(&lh[kv[i] >> 24], 1);
    }
    __syncthreads();
    h[threadIdx.x * nblk + blockIdx.x] = lh[threadIdx.x];
}

template <int SH, bool PACK>
__global__ __launch_bounds__(256) void rscat_kernel(const unsigned* __restrict__ in,
                                                    const int* __restrict__ srcp,
                                                    const int* __restrict__ dstp,
                                                    unsigned* __restrict__ outv,
                                                    const int* __restrict__ scanned,
                                                    int E, int nblk) {
    __shared__ unsigned items[1024];
    __shared__ unsigned sorted[1024];
    __shared__ int lh[256], lstart[256], rbase[256];
    __shared__ int wcnt[4][256];

    int tid = threadIdx.x, blk = blockIdx.x;
    int base = blk * 1024;
    int k = min(1024, E - base);
    lh[tid] = 0;
    rbase[tid] = 0;
#pragma unroll
    for (int j = 0; j < 4; ++j) {
        int idx = j * 256 + tid;
        unsigned v = 0u;
        if (base + idx < E) {
            if constexpr (PACK)
                v = ((unsigned)dstp[base + idx] << 16) | (unsigned)srcp[base + idx];
            else
                v = in[base + idx];
        }
        items[idx] = v;
    }
    __syncthreads();
#pragma unroll
    for (int j = 0; j < 4; ++j) {
        int idx = j * 256 + tid;
        if (idx < k) atomicAdd(&lh[(items[idx] >> SH) & 255], 1);
    }
    __syncthreads();
    int sv = lh[tid];
    lstart[tid] = sv;
    __syncthreads();
    for (int off = 1; off < 256; off <<= 1) {
        int y = (tid >= off) ? lstart[tid - off] : 0;
        __syncthreads();
        lstart[tid] += y;
        __syncthreads();
    }
    int excl = lstart[tid] - sv;
    __syncthreads();
    lstart[tid] = excl;
    __syncthreads();

    int lane = tid & 63, wave = tid >> 6;
#pragma unroll
    for (int it = 0; it < 4; ++it) {
        int idx = it * 256 + tid;
        unsigned v = items[idx];
        int d = (v >> SH) & 255;
        bool valid = idx < k;
        unsigned long long m = __ballot(valid);
#pragma unroll
        for (int b = 0; b < 8; ++b) {
            unsigned long long bb = __ballot((d >> b) & 1);
            m &= ((d >> b) & 1) ? bb : ~bb;
        }
        int lanerank = __popcll(m & ((1ull << lane) - 1ull));
        int wtot = __popcll(m);
        wcnt[0][tid] = 0; wcnt[1][tid] = 0; wcnt[2][tid] = 0; wcnt[3][tid] = 0;
        __syncthreads();
        if (valid && lanerank == 0) wcnt[wave][d] = wtot;
        __syncthreads();
        if (valid) {
            int cw = 0;
            for (int w = 0; w < wave; ++w) cw += wcnt[w][d];
            sorted[lstart[d] + rbase[d] + cw + lanerank] = v;
        }
        __syncthreads();
        rbase[tid] += wcnt[0][tid] + wcnt[1][tid] + wcnt[2][tid] + wcnt[3][tid];
        __syncthreads();
    }
#pragma unroll
    for (int j = 0; j < 4; ++j) {
        int i = j * 256 + tid;
        if (i < k) {
            unsigned v = sorted[i];
            int d = (v >> SH) & 255;
            outv[scanned[d * nblk + blk] + (i - lstart[d])] = v;
        }
    }
}

// ---------------- row pointers from sorted kv ----------------

__global__ void rp_kernel(const unsigned* __restrict__ kv, int* __restrict__ rp,
                          int E, int N) {
    int i = blockIdx.x * 256 + threadIdx.x;
    if (i >= E) return;
    int cur = (int)(kv[i] >> 16);
    int prev = (i == 0) ? -1 : (int)(kv[i - 1] >> 16);
    for (int t = prev + 1; t <= cur; ++t) rp[t] = i;
    if (i == E - 1)
        for (int t = cur + 1; t <= N; ++t) rp[t] = E;
}

// ---------------- global per-head max of alS (128 blocks -> few atomics) ----------

template <int H>
__global__ __launch_bounds__(256) void gmax_kernel(const float* __restrict__ a,
                                                   unsigned* __restrict__ gm, int total) {
    __shared__ unsigned sm[256];
    unsigned loc = 0;
    int stride = 256 * gridDim.x;
    for (int i = blockIdx.x * 256 + threadIdx.x; i < total; i += stride)
        loc = max(loc, fkey(a[i]));
    sm[threadIdx.x] = loc;
    __syncthreads();
    for (int off = 128; off >= H; off >>= 1) {
        if (threadIdx.x < off) sm[threadIdx.x] = max(sm[threadIdx.x], sm[threadIdx.x + off]);
        __syncthreads();
    }
    if (threadIdx.x < H) atomicMax(&gm[threadIdx.x], sm[threadIdx.x]);
}

// ---------------- edge-weight precompute ----------------
// layer 1: one thread per edge; writes TRANSPOSED fp16 w1t[h*E+e] (8 coalesced streams)

__global__ __launch_bounds__(256) void w1_kernel(const unsigned* __restrict__ kv,
                                                 const float* __restrict__ alS,
                                                 const float* __restrict__ alD,
                                                 const unsigned* __restrict__ gm,
                                                 __half* __restrict__ w1t, int E) {
    int e = blockIdx.x * 256 + threadIdx.x;
    if (e >= E) return;
    unsigned k = kv[e];
    int s = (int)(k & 0xFFFFu), t = (int)(k >> 16);
    float sv[8], dv[8];
    *(f32x4*)&sv[0] = *(const f32x4*)(alS + (size_t)s * 8);
    *(f32x4*)&sv[4] = *(const f32x4*)(alS + (size_t)s * 8 + 4);
    *(f32x4*)&dv[0] = *(const f32x4*)(alD + (size_t)t * 8);
    *(f32x4*)&dv[4] = *(const f32x4*)(alD + (size_t)t * 8 + 4);
#pragma unroll
    for (int h = 0; h < 8; ++h) {
        float m = lrelu(funkey(gm[h]) + dv[h]);
        w1t[(size_t)h * E + e] = __float2half(__expf(lrelu(sv[h] + dv[h]) - m));
    }
}

__global__ void w2_kernel(const unsigned* __restrict__ kv, const float* __restrict__ alS,
                          const float* __restrict__ alD, const unsigned* __restrict__ gm,
                          float* __restrict__ w2v, int E) {
    int e = blockIdx.x * 256 + threadIdx.x;
    if (e >= E) return;
    unsigned k = kv[e];
    int s = (int)(k & 0xFFFFu), t = (int)(k >> 16);
    float adT = alD[t];
    w2v[e] = __expf(lrelu(alS[s] + adT) - lrelu(funkey(gm[0]) + adT));
}

// ---------------- MFMA GEMM: C[M,128(half)] = A[M,128] @ B[128,NC(f32)] ------------
// FUSE_AL2: also emit alS[r]=C[r,:]·as, alD[r]=C[r,:]·ad from fp32 accumulators.

template <int NC, typename AT, bool FUSE_AL2>
__global__ __launch_bounds__(256) void gemm_mfma(const AT* __restrict__ A,
                                                 const float* __restrict__ B,
                                                 __half* __restrict__ C, int M,
                                                 const float* __restrict__ as,
                                                 const float* __restrict__ ad,
                                                 float* __restrict__ alS,
                                                 float* __restrict__ alD) {
    __shared__ __half Bt[128][136];

    {
        int t = threadIdx.x;
        int c = t & 127;
        int kq = t >> 7;
#pragma unroll
        for (int ch = 0; ch < 8; ++ch) {
            int k0 = kq * 64 + ch * 8;
            half8v hv;
#pragma unroll
            for (int j = 0; j < 8; ++j) {
                float v = (c < NC) ? B[(size_t)(k0 + j) * NC + c] : 0.0f;
                hv[j] = (__fp16)v;
            }
            *(half8v*)&Bt[c][k0] = hv;
        }
    }
    __syncthreads();

    const int wid = threadIdx.x >> 6;
    const int lane = threadIdx.x & 63;
    const int li = lane & 15;
    const int lg = lane >> 4;

    int row = blockIdx.x * 64 + wid * 16 + li;
    int rowc = min(row, M - 1);

    half8v a[4];
#pragma unroll
    for (int ks = 0; ks < 4; ++ks) {
        int q = ks * 4 + lg;
        if constexpr (sizeof(AT) == 2) {
            a[ks] = *((const half8v*)(A + (size_t)rowc * 128) + q);
        } else {
            const float4* p = (const float4*)(A + (size_t)rowc * 128) + 2 * q;
            float4 a0 = p[0], a1 = p[1];
            half8v hv;
            hv[0] = (__fp16)a0.x; hv[1] = (__fp16)a0.y; hv[2] = (__fp16)a0.z; hv[3] = (__fp16)a0.w;
            hv[4] = (__fp16)a1.x; hv[5] = (__fp16)a1.y; hv[6] = (__fp16)a1.z; hv[7] = (__fp16)a1.w;
            a[ks] = hv;
        }
    }

    f32x4 acc[8];
#pragma unroll
    for (int ct = 0; ct < 8; ++ct) acc[ct] = (f32x4)0.0f;

#pragma unroll
    for (int ks = 0; ks < 4; ++ks) {
#pragma unroll
        for (int ct = 0; ct < 8; ++ct) {
            half8v b = *(const half8v*)&Bt[ct * 16 + li][ks * 32 + 8 * lg];
            acc[ct] = __builtin_amdgcn_mfma_f32_16x16x32_f16(a[ks], b, acc[ct], 0, 0, 0);
        }
    }

    int orow = blockIdx.x * 64 + wid * 16 + 4 * lg;
#pragma unroll
    for (int ct = 0; ct < 8; ++ct) {
#pragma unroll
        for (int r = 0; r < 4; ++r) {
            int rr = orow + r;
            if (rr < M) C[(size_t)rr * 128 + ct * 16 + li] = __float2half(acc[ct][r]);
        }
    }

    if constexpr (FUSE_AL2) {
        float asv[8], adv[8];
#pragma unroll
        for (int ct = 0; ct < 8; ++ct) {
            int c = ct * 16 + li;
            asv[ct] = (c < NC) ? as[c] : 0.0f;
            adv[ct] = (c < NC) ? ad[c] : 0.0f;
        }
#pragma unroll
        for (int r = 0; r < 4; ++r) {
            float s = 0.f, d = 0.f;
#pragma unroll
            for (int ct = 0; ct < 8; ++ct) {
                s = fmaf(acc[ct][r], asv[ct], s);
                d = fmaf(acc[ct][r], adv[ct], d);
            }
            s += __shfl_down(s, 8); d += __shfl_down(d, 8);
            s += __shfl_down(s, 4); d += __shfl_down(d, 4);
            s += __shfl_down(s, 2); d += __shfl_down(d, 2);
            s += __shfl_down(s, 1); d += __shfl_down(d, 1);
            if (li == 0) {
                int rr = orow + r;
                if (rr < M) { alS[rr] = s; alD[rr] = d; }
            }
        }
    }
}

// ---------------- layer-1 attention logits (standalone, coalesced) ----------------

__global__ void al1_kernel(const __half* __restrict__ h1h, const float* __restrict__ as,
                           const float* __restrict__ ad, float* __restrict__ alS,
                           float* __restrict__ alD, int N) {
    int g = blockIdx.x * 256 + threadIdx.x;
    if (g >= N * 8) return;
    int r = g >> 3, h = g & 7;
    const __half2* hp = (const __half2*)(h1h + (size_t)r * 128 + h * 16);
    const float* sp = as + h * 16;
    const float* dp = ad + h * 16;
    float s = 0.f, d = 0.f;
#pragma unroll
    for (int q = 0; q < 8; ++q) {
        float2 v = __half22float2(hp[q]);
        s = fmaf(v.x, sp[2 * q], s);
        d = fmaf(v.x, dp[2 * q], d);
        s = fmaf(v.y, sp[2 * q + 1], s);
        d = fmaf(v.y, dp[2 * q + 1], d);
    }
    alS[g] = s;
    alD[g] = d;
}

// ---------------- layer-1 aggregation: fp16 weights, unroll 16/8/4/1 ----------------

__global__ __launch_bounds__(256) void agg1_kernel(
    const __half* __restrict__ h1h, const float* __restrict__ alS,
    const float* __restrict__ alD, const float* __restrict__ b1,
    const int* __restrict__ rp, const unsigned* __restrict__ kv,
    const __half* __restrict__ w1t, const unsigned* __restrict__ gm,
    __half* __restrict__ h2h, int N, int E) {
    int t = blockIdx.x * 4 + (threadIdx.x >> 6);
    int lane = threadIdx.x & 63;
    int h = lane >> 3;

    float adh = alD[t * 8 + h];
    float mh = lrelu(funkey(gm[h]) + adh);
    int e0 = rp[t], e1 = rp[t + 1];

    float ex = __expf(lrelu(alS[t * 8 + h] + adh) - mh);  // self loop (fp32)
    float dsum = ex, dsum2 = 0.f;
    float2 hs = __half22float2(*(const __half2*)(h1h + (size_t)t * 128 + 2 * lane));
    float fx = ex * hs.x, fy = ex * hs.y;
    const __half* wrow = w1t + (size_t)h * E;

    int e = e0;
    while (e < e1 && (e & 3)) {
        int s0 = (int)(kv[e] & 0xFFFFu);
        float w0 = __half2float(wrow[e]);
        float2 f0 = __half22float2(*(const __half2*)(h1h + (size_t)s0 * 128 + 2 * lane));
        dsum2 += w0;
        fx = fmaf(w0, f0.x, fx); fy = fmaf(w0, f0.y, fy);
        ++e;
    }
    for (; e + 16 <= e1; e += 16) {
        uint4u kk[4];
        float ww[16];
#pragma unroll
        for (int q = 0; q < 4; ++q) {
            kk[q] = *(const uint4u*)&kv[e + 4 * q];
            half4v wv = *(const half4v*)&wrow[e + 4 * q];
#pragma unroll
            for (int r = 0; r < 4; ++r) ww[q * 4 + r] = (float)wv[r];
        }
        float2 ff[16];
#pragma unroll
        for (int q = 0; q < 4; ++q)
#pragma unroll
            for (int r = 0; r < 4; ++r)
                ff[q * 4 + r] = __half22float2(
                    *(const __half2*)(h1h + (size_t)(kk[q][r] & 0xFFFFu) * 128 + 2 * lane));
#pragma unroll
        for (int q = 0; q < 4; ++q) {
            if (q & 1) dsum2 += (ww[q * 4] + ww[q * 4 + 1]) + (ww[q * 4 + 2] + ww[q * 4 + 3]);
            else       dsum  += (ww[q * 4] + ww[q * 4 + 1]) + (ww[q * 4 + 2] + ww[q * 4 + 3]);
#pragma unroll
            for (int r = 0; r < 4; ++r) {
                float w = ww[q * 4 + r];
                float2 f = ff[q * 4 + r];
                fx = fmaf(w, f.x, fx);
                fy = fmaf(w, f.y, fy);
            }
        }
    }
    if (e + 8 <= e1) {
        uint4u ka = *(const uint4u*)&kv[e];
        uint4u kb = *(const uint4u*)&kv[e + 4];
        half4v wva = *(const half4v*)&wrow[e];
        half4v wvb = *(const half4v*)&wrow[e + 4];
        float2 f0 = __half22float2(*(const __half2*)(h1h + (size_t)(ka.x & 0xFFFFu) * 128 + 2 * lane));
        float2 f1 = __half22float2(*(const __half2*)(h1h + (size_t)(ka.y & 0xFFFFu) * 128 + 2 * lane));
        float2 f2 = __half22float2(*(const __half2*)(h1h + (size_t)(ka.z & 0xFFFFu) * 128 + 2 * lane));
        float2 f3 = __half22float2(*(const __half2*)(h1h + (size_t)(ka.w & 0xFFFFu) * 128 + 2 * lane));
        float2 f4 = __half22float2(*(const __half2*)(h1h + (size_t)(kb.x & 0xFFFFu) * 128 + 2 * lane));
        float2 f5 = __half22float2(*(const __half2*)(h1h + (size_t)(kb.y & 0xFFFFu) * 128 + 2 * lane));
        float2 f6 = __half22float2(*(const __half2*)(h1h + (size_t)(kb.z & 0xFFFFu) * 128 + 2 * lane));
        float2 f7 = __half22float2(*(const __half2*)(h1h + (size_t)(kb.w & 0xFFFFu) * 128 + 2 * lane));
        float w0 = (float)wva[0], w1 = (float)wva[1], w2 = (float)wva[2], w3 = (float)wva[3];
        float w4 = (float)wvb[0], w5 = (float)wvb[1], w6 = (float)wvb[2], w7 = (float)wvb[3];
        dsum += (w0 + w1) + (w2 + w3);
        dsum2 += (w4 + w5) + (w6 + w7);
        fx = fmaf(w0, f0.x, fx); fy = fmaf(w0, f0.y, fy);
        fx = fmaf(w1, f1.x, fx); fy = fmaf(w1, f1.y, fy);
        fx = fmaf(w2, f2.x, fx); fy = fmaf(w2, f2.y, fy);
        fx = fmaf(w3, f3.x, fx); fy = fmaf(w3, f3.y, fy);
        fx = fmaf(w4, f4.x, fx); fy = fmaf(w4, f4.y, fy);
        fx = fmaf(w5, f5.x, fx); fy = fmaf(w5, f5.y, fy);
        fx = fmaf(w6, f6.x, fx); fy = fmaf(w6, f6.y, fy);
        fx = fmaf(w7, f7.x, fx); fy = fmaf(w7, f7.y, fy);
        e += 8;
    }
    if (e + 4 <= e1) {
        uint4u ka = *(const uint4u*)&kv[e];
        half4v wva = *(const half4v*)&wrow[e];
        float2 f0 = __half22float2(*(const __half2*)(h1h + (size_t)(ka.x & 0xFFFFu) * 128 + 2 * lane));
        float2 f1 = __half22float2(*(const __half2*)(h1h + (size_t)(ka.y & 0xFFFFu) * 128 + 2 * lane));
        float2 f2 = __half22float2(*(const __half2*)(h1h + (size_t)(ka.z & 0xFFFFu) * 128 + 2 * lane));
        float2 f3 = __half22float2(*(const __half2*)(h1h + (size_t)(ka.w & 0xFFFFu) * 128 + 2 * lane));
        float w0 = (float)wva[0], w1 = (float)wva[1], w2 = (float)wva[2], w3 = (float)wva[3];
        dsum += (w0 + w1) + (w2 + w3);
        fx = fmaf(w0, f0.x, fx); fy = fmaf(w0, f0.y, fy);
        fx = fmaf(w1, f1.x, fx); fy = fmaf(w1, f1.y, fy);
        fx = fmaf(w2, f2.x, fx); fy = fmaf(w2, f2.y, fy);
        fx = fmaf(w3, f3.x, fx); fy = fmaf(w3, f3.y, fy);
        e += 4;
    }
    for (; e < e1; ++e) {
        int s0 = (int)(kv[e] & 0xFFFFu);
        float w0 = __half2float(wrow[e]);
        float2 f0 = __half22float2(*(const __half2*)(h1h + (size_t)s0 * 128 + 2 * lane));
        dsum2 += w0;
        fx = fmaf(w0, f0.x, fx); fy = fmaf(w0, f0.y, fy);
    }
    dsum += dsum2;
    float inv = 1.0f / dsum;
    float2 bb = *(const float2*)(b1 + 2 * lane);
    float ox = fmaxf(fmaf(fx, inv, bb.x), 0.0f);
    float oy = fmaxf(fmaf(fy, inv, bb.y), 0.0f);
    *(__half2*)(h2h + (size_t)t * 128 + 2 * lane) = __floats2half2_rn(ox, oy);
}

// ---------------- layer-2 aggregation: unroll 16/8/4/1 ----------------

__global__ __launch_bounds__(256) void agg2_kernel(
    const __half* __restrict__ h3h, const float* __restrict__ alS,
    const float* __restrict__ alD, const float* __restrict__ b2,
    const int* __restrict__ rp, const unsigned* __restrict__ kv,
    const float* __restrict__ w2v, const unsigned* __restrict__ gm,
    float* __restrict__ out, int N, int NC) {
    int t = blockIdx.x * 4 + (threadIdx.x >> 6);
    int lane = threadIdx.x & 63;

    float adT = alD[t];
    float m = lrelu(funkey(gm[0]) + adT);
    int e0 = rp[t], e1 = rp[t + 1];

    float ex = __expf(lrelu(alS[t] + adT) - m);
    float dsum = ex, dsum2 = 0.f;
    float2 hs = __half22float2(*(const __half2*)(h3h + (size_t)t * 128 + 2 * lane));
    float fx = ex * hs.x, fy = ex * hs.y;  // pad cols are 0

    int e = e0;
    for (; e + 16 <= e1; e += 16) {
        uint4u kk[4];
        f32x4u ww[4];
#pragma unroll
        for (int q = 0; q < 4; ++q) {
            kk[q] = *(const uint4u*)&kv[e + 4 * q];
            ww[q] = *(const f32x4u*)&w2v[e + 4 * q];
        }
        float2 ff[16];
#pragma unroll
        for (int q = 0; q < 4; ++q)
#pragma unroll
            for (int r = 0; r < 4; ++r)
                ff[q * 4 + r] = __half22float2(
                    *(const __half2*)(h3h + (size_t)(kk[q][r] & 0xFFFFu) * 128 + 2 * lane));
#pragma unroll
        for (int q = 0; q < 4; ++q) {
            if (q & 1) dsum2 += (ww[q][0] + ww[q][1]) + (ww[q][2] + ww[q][3]);
            else       dsum  += (ww[q][0] + ww[q][1]) + (ww[q][2] + ww[q][3]);
#pragma unroll
            for (int r = 0; r < 4; ++r) {
                float w = ww[q][r];
                float2 f = ff[q * 4 + r];
                fx = fmaf(w, f.x, fx);
                fy = fmaf(w, f.y, fy);
            }
        }
    }
    if (e + 8 <= e1) {
        uint4u ka = *(const uint4u*)&kv[e];
        uint4u kb = *(const uint4u*)&kv[e + 4];
        f32x4u wa = *(const f32x4u*)&w2v[e];
        f32x4u wb = *(const f32x4u*)&w2v[e + 4];
        float2 f0 = __half22float2(*(const __half2*)(h3h + (size_t)(ka.x & 0xFFFFu) * 128 + 2 * lane));
        float2 f1 = __half22float2(*(const __half2*)(h3h + (size_t)(ka.y & 0xFFFFu) * 128 + 2 * lane));
        float2 f2 = __half22float2(*(const __half2*)(h3h + (size_t)(ka.z & 0xFFFFu) * 128 + 2 * lane));
        float2 f3 = __half22float2(*(const __half2*)(h3h + (size_t)(ka.w & 0xFFFFu) * 128 + 2 * lane));
        float2 f4 = __half22float2(*(const __half2*)(h3h + (size_t)(kb.x & 0xFFFFu) * 128 + 2 * lane));
        float2 f5 = __half22float2(*(const __half2*)(h3h + (size_t)(kb.y & 0xFFFFu) * 128 + 2 * lane));
        float2 f6 = __half22float2(*(const __half2*)(h3h + (size_t)(kb.z & 0xFFFFu) * 128 + 2 * lane));
        float2 f7 = __half22float2(*(const __half2*)(h3h + (size_t)(kb.w & 0xFFFFu) * 128 + 2 * lane));
        dsum += (wa[0] + wa[1]) + (wa[2] + wa[3]);
        dsum2 += (wb[0] + wb[1]) + (wb[2] + wb[3]);
        fx = fmaf(wa[0], f0.x, fx); fy = fmaf(wa[0], f0.y, fy);
        fx = fmaf(wa[1], f1.x, fx); fy = fmaf(wa[1], f1.y, fy);
        fx = fmaf(wa[2], f2.x, fx); fy = fmaf(wa[2], f2.y, fy);
        fx = fmaf(wa[3], f3.x, fx); fy = fmaf(wa[3], f3.y, fy);
        fx = fmaf(wb[0], f4.x, fx); fy = fmaf(wb[0], f4.y, fy);
        fx = fmaf(wb[1], f5.x, fx); fy = fmaf(wb[1], f5.y, fy);
        fx = fmaf(wb[2], f6.x, fx); fy = fmaf(wb[2], f6.y, fy);
        fx = fmaf(wb[3], f7.x, fx); fy = fmaf(wb[3], f7.y, fy);
        e += 8;
    }
    if (e + 4 <= e1) {
        uint4u ka = *(const uint4u*)&kv[e];
        f32x4u wa = *(const f32x4u*)&w2v[e];
        float2 f0 = __half22float2(*(const __half2*)(h3h + (size_t)(ka.x & 0xFFFFu) * 128 + 2 * lane));
        float2 f1 = __half22float2(*(const __half2*)(h3h + (size_t)(ka.y & 0xFFFFu) * 128 + 2 * lane));
        float2 f2 = __half22float2(*(const __half2*)(h3h + (size_t)(ka.z & 0xFFFFu) * 128 + 2 * lane));
        float2 f3 = __half22float2(*(const __half2*)(h3h + (size_t)(ka.w & 0xFFFFu) * 128 + 2 * lane));
        dsum += (wa[0] + wa[1]) + (wa[2] + wa[3]);
        fx = fmaf(wa[0], f0.x, fx); fy = fmaf(wa[0], f0.y, fy);
        fx = fmaf(wa[1], f1.x, fx); fy = fmaf(wa[1], f1.y, fy);
        fx = fmaf(wa[2], f2.x, fx); fy = fmaf(wa[2], f2.y, fy);
        fx = fmaf(wa[3], f3.x, fx); fy = fmaf(wa[3], f3.y, fy);
        e += 4;
    }
    for (; e < e1; ++e) {
        int s0 = (int)(kv[e] & 0xFFFFu);
        float w0 = w2v[e];
        float2 f0 = __half22float2(*(const __half2*)(h3h + (size_t)s0 * 128 + 2 * lane));
        dsum2 += w0;
        fx = fmaf(w0, f0.x, fx); fy = fmaf(w0, f0.y, fy);
    }
    dsum += dsum2;
    float inv = 1.0f / dsum;
    int c0 = 2 * lane, c1 = 2 * lane + 1;
    if (c0 < NC) out[(size_t)t * NC + c0] = fmaf(fx, inv, b2[c0]);
    if (c1 < NC) out[(size_t)t * NC + c1] = fmaf(fy, inv, b2[c1]);
}

// ---------------- host launcher ----------------

extern "C" void kernel_launch(void* const* d_in, const int* in_sizes, int n_in,
                              void* d_out, int out_size, void* d_ws, size_t ws_size,
                              hipStream_t stream) {
    const float* x   = (const float*)d_in[0];
    const int*   ei  = (const int*)d_in[1];
    const float* W1  = (const float*)d_in[2];
    const float* aS1 = (const float*)d_in[3];
    const float* aD1 = (const float*)d_in[4];
    const float* b1  = (const float*)d_in[5];
    const float* W2  = (const float*)d_in[6];
    const float* aS2 = (const float*)d_in[7];
    const float* aD2 = (const float*)d_in[8];
    const float* b2  = (const float*)d_in[9];
    float* out = (float*)d_out;

    const int N = in_sizes[0] / 128;   // 50000
    const int E = in_sizes[1] / 2;     // 800000
    const int NC2 = 121;

    const int NBLK = (E + 1023) / 1024;        // 782
    const int HN = 256 * NBLK;                 // 200192

    size_t off = 0;
    auto alloc = [&](size_t bytes) {
        size_t o = off;
        off = (off + bytes + 255) & ~(size_t)255;
        return o;
    };
    char* ws = (char*)d_ws;
    unsigned* kv0  = (unsigned*)(ws + alloc((size_t)E * 4));
    unsigned* kv1  = (unsigned*)(ws + alloc((size_t)E * 4));
    int*      h    = (int*)(ws + alloc((size_t)(HN + 1) * 4));
    int*      hs   = (int*)(ws + alloc((size_t)(HN + 1) * 4));
    int*      bsum = (int*)(ws + alloc(256 * 4));
    int*      rp   = (int*)(ws + alloc((size_t)(N + 1) * 4));
    float*    alS1 = (float*)(ws + alloc((size_t)N * 8 * 4));
    float*    alD1 = (float*)(ws + alloc((size_t)N * 8 * 4));
    float*    alS2 = (float*)(ws + alloc((size_t)N * 4));
    float*    alD2 = (float*)(ws + alloc((size_t)N * 4));
    unsigned* gm1  = (unsigned*)(ws + alloc(8 * 4));
    unsigned* gm2  = (unsigned*)(ws + alloc(4));
    __half*   w1t  = (__half*)(ws + alloc((size_t)E * 8 * 2));
    __half*   h1h  = (__half*)(ws + alloc((size_t)N * 128 * 2));
    __half*   h2h  = (__half*)(ws + alloc((size_t)N * 128 * 2));
    __half*   h3h  = h1h;              // h1h dead after agg1; reuse
    float*    w2v  = (float*)kv1;      // kv1 dead after sort; reuse
    if (ws_size < off) return;

    const int* src = ei;
    const int* dst = ei + E;

    hipMemsetAsync(gm1, 0, 8 * 4, stream);
    hipMemsetAsync(gm2, 0, 4, stream);

    int eb = (E + 255) / 256;
    int snb = (HN + 1023) / 1024;  // 196 <= 256

    // radix sort by dst (bytes 2 then 3); pass1 packs (dst<<16)|src on the fly
    rhist1_kernel<<<NBLK, 256, 0, stream>>>(dst, h, E, NBLK);
    scan_reduce<<<snb, 256, 0, stream>>>(h, bsum, HN);
    scan_write2<<<snb, 256, 0, stream>>>(h, bsum, hs, HN);
    rscat_kernel<16, true><<<NBLK, 256, 0, stream>>>(nullptr, src, dst, kv1, hs, E, NBLK);
    rhist2_kernel<<<NBLK, 256, 0, stream>>>(kv1, h, E, NBLK);
    scan_reduce<<<snb, 256, 0, stream>>>(h, bsum, HN);
    scan_write2<<<snb, 256, 0, stream>>>(h, bsum, hs, HN);
    rscat_kernel<24, false><<<NBLK, 256, 0, stream>>>(kv1, nullptr, nullptr, kv0, hs, E, NBLK);
    rp_kernel<<<eb, 256, 0, stream>>>(kv0, rp, E, N);

    int gmb = (N + 63) / 64;
    int ab = (N + 3) / 4;
    gemm_mfma<128, float, false><<<gmb, 256, 0, stream>>>(x, W1, h1h, N,
                                                          nullptr, nullptr, nullptr, nullptr);
    al1_kernel<<<(N * 8 + 255) / 256, 256, 0, stream>>>(h1h, aS1, aD1, alS1, alD1, N);
    gmax_kernel<8><<<128, 256, 0, stream>>>(alS1, gm1, N * 8);
    w1_kernel<<<eb, 256, 0, stream>>>(kv0, alS1, alD1, gm1, w1t, E);
    agg1_kernel<<<ab, 256, 0, stream>>>(h1h, alS1, alD1, b1, rp, kv0, w1t, gm1, h2h, N, E);

    gemm_mfma<121, __half, true><<<gmb, 256, 0, stream>>>(h2h, W2, h3h, N,
                                                          aS2, aD2, alS2, alD2);
    gmax_kernel<1><<<128, 256, 0, stream>>>(alS2, gm2, N);
    w2_kernel<<<eb, 256, 0, stream>>>(kv0, alS2, alD2, gm2, w2v, E);
    agg2_kernel<<<ab, 256, 0, stream>>>(h3h, alS2, alD2, b2, rp, kv0, w2v, gm2, out, N, NC2);
}